// Round 9
// baseline (1931.606 us; speedup 1.0000x reference)
//
#include <hip/hip_runtime.h>

// ---------------------------------------------------------------------------
// MEASUREMENT ROUND 2: round-8 pipeline with idempotent internal repeats
// (gemm x6, lif x40, readout x80) to surface per-kernel counters above the
// harness fill dispatches. Divide dur/FETCH by rep count.
// ---------------------------------------------------------------------------

typedef float  f32x4  __attribute__((ext_vector_type(4)));
typedef short  short8 __attribute__((ext_vector_type(8)));
typedef unsigned long long ull;

#define B_   256
#define T_   1000
#define K_   700
#define H_   64
#define O_   20
#define NKT  11          // ceil(700/64) k-tiles of BK=64
#define NCH  200         // v_ro chunks
#define TCH  5           // chunk length (NCH*TCH = T_)
#define TCL  100         // LIF chunk length
#define NCL  10          // LIF chunks
#define BIL  40          // LIF burn-in steps

#define REP_G 6
#define REP_L 40
#define REP_R 80

// workspace layout (bytes)
#define OFF_WFRAG  ((size_t)0)            // 11*16384 = 180,224
#define OFF_CUR    ((size_t)262144)       // 256000*64*4 = 65,536,000
#define OFF_MASK   ((size_t)65798144)     // 256000*8    =  2,048,000

// ---------------------------------------------------------------------------
// k0: pack W_h into fragment-ordered split-bf16 (BK=64 tiles, zero-pad k>=700).
// ---------------------------------------------------------------------------
__global__ void wprep(const float* __restrict__ Wh, unsigned short* __restrict__ wfrag) {
    int e = blockIdx.x * 256 + threadIdx.x;          // 22*256 = 5632 exact
    int kt   = e >> 9;
    int rem  = e & 511;
    int nf   = rem >> 7;
    int kf   = (rem >> 6) & 1;
    int lane = rem & 63;
    int h     = nf * 16 + (lane & 15);
    int kbase = kt * 64 + kf * 32 + ((lane >> 4) & 3) * 8;
    int slot  = (nf * 2 + kf) * 64 + lane;
    unsigned short* dh = wfrag + (size_t)kt * 8192 + slot * 8;
    unsigned short* dl = dh + 4096;
#pragma unroll
    for (int j = 0; j < 8; ++j) {
        int k = kbase + j;
        float v = (k < K_) ? Wh[(size_t)h * K_ + k] : 0.0f;
        unsigned u  = __builtin_bit_cast(unsigned, v);
        float    fh = __builtin_bit_cast(float, u & 0xffff0000u);
        float    r  = v - fh;
        dh[j] = (unsigned short)(u >> 16);
        dl[j] = (unsigned short)(__builtin_bit_cast(unsigned, r) >> 16);
    }
}

// ---------------------------------------------------------------------------
// k1: GEMM (round-8 structure, x REP_G repeats)
// ---------------------------------------------------------------------------
__device__ __forceinline__ void glds16(const void* src, void* lds) {
    __builtin_amdgcn_global_load_lds(
        (const __attribute__((address_space(1))) void*)src,
        (__attribute__((address_space(3))) void*)lds, 16, 0, 0);
}

__device__ __forceinline__ void splitpair(f32x4 p0, f32x4 p1, short8& hi, short8& lo) {
#pragma unroll
    for (int j = 0; j < 4; ++j) {
        {
            unsigned u  = __builtin_bit_cast(unsigned, p0[j]);
            float    fh = __builtin_bit_cast(float, u & 0xffff0000u);
            float    r  = p0[j] - fh;
            hi[j] = (short)(u >> 16);
            lo[j] = (short)(__builtin_bit_cast(unsigned, r) >> 16);
        }
        {
            unsigned u  = __builtin_bit_cast(unsigned, p1[j]);
            float    fh = __builtin_bit_cast(float, u & 0xffff0000u);
            float    r  = p1[j] - fh;
            hi[j + 4] = (short)(u >> 16);
            lo[j + 4] = (short)(__builtin_bit_cast(unsigned, r) >> 16);
        }
    }
}

__device__ __forceinline__ void stage_x64(const float* __restrict__ x, size_t row0,
                                          int kt, int tid, float* sbuf) {
#pragma unroll
    for (int j = 0; j < 4; ++j) {
        int id = j * 256 + tid;                  // 0..1023
        int s  = id >> 9;                        // k-half
        int r  = (id >> 3) & 63;                 // row
        int pc = id & 7;                         // phys chunk in 128B
        int c  = pc ^ (r & 7);                   // logical chunk
        int kbyte = kt * 256 + s * 128 + (c << 4);
        if (kbyte + 16 > K_ * 4) kbyte = 0;      // tail clamp; value * W_pad(0) = 0
        const char* src = (const char*)(x + (row0 + r) * (size_t)K_) + kbyte;
        float* dst = sbuf + (size_t)(id & ~63) * 4;   // wave-uniform base + lane*16B
        glds16(src, dst);
    }
}

__device__ __forceinline__ void stage_w64(const unsigned short* __restrict__ wfrag,
                                          int kt, int tid, unsigned short* sbuf) {
#pragma unroll
    for (int j = 0; j < 4; ++j) {
        int id = j * 256 + tid;                  // 0..1023 chunks
        const unsigned short* src = wfrag + (size_t)kt * 8192 + id * 8;
        unsigned short* dst = sbuf + (size_t)(id & ~63) * 8;
        glds16(src, dst);
    }
}

__device__ __forceinline__ void compute64(const float* sbx_, const unsigned short* sbw_,
                                          int lane, int wid, f32x4 (&acc)[4]) {
    const char*   xb = (const char*)sbx_;
    const short8* wb = (const short8*)sbw_;      // hi chunks 0..511, lo 512..1023
    int rloc = wid * 16 + (lane & 15);
    int g2   = ((lane >> 4) & 3) * 2;
#pragma unroll
    for (int kf = 0; kf < 2; ++kf) {
        const char* base = xb + kf * 8192 + rloc * 128;
        int c0 = g2 ^ (rloc & 7);
        int c1 = (g2 + 1) ^ (rloc & 7);
        f32x4 p0 = *(const f32x4*)(base + c0 * 16);
        f32x4 p1 = *(const f32x4*)(base + c1 * 16);
        short8 ah, al;
        splitpair(p0, p1, ah, al);
#pragma unroll
        for (int n = 0; n < 4; ++n) {
            short8 bhf = wb[(n * 2 + kf) * 64 + lane];
            short8 blf = wb[(n * 2 + kf) * 64 + lane + 512];
            acc[n] = __builtin_amdgcn_mfma_f32_16x16x32_bf16(ah, bhf, acc[n], 0, 0, 0);
            acc[n] = __builtin_amdgcn_mfma_f32_16x16x32_bf16(al, bhf, acc[n], 0, 0, 0);
            acc[n] = __builtin_amdgcn_mfma_f32_16x16x32_bf16(ah, blf, acc[n], 0, 0, 0);
        }
    }
}

__global__ __launch_bounds__(256, 2) void gemm_cur(const float* __restrict__ x,
                                                   const unsigned short* __restrict__ wfrag,
                                                   const float* __restrict__ b_h,
                                                   float* __restrict__ cur) {
    __shared__ float          sbx[2][4096];   // 2 x 16KB x-tiles
    __shared__ unsigned short sbw[2][8192];   // 2 x 16KB W-tiles
    int tid  = threadIdx.x;
    int lane = tid & 63;
    int wid  = tid >> 6;             // 0..3
    size_t row0 = (size_t)blockIdx.x * 64;

    float bh4[4];
#pragma unroll
    for (int n = 0; n < 4; ++n) bh4[n] = b_h[n * 16 + (lane & 15)];

    for (int rep = 0; rep < REP_G; ++rep) {
        __syncthreads();     // protect LDS reuse across reps

        f32x4 acc[4];
#pragma unroll
        for (int n = 0; n < 4; ++n) acc[n] = (f32x4){0.f, 0.f, 0.f, 0.f};

        stage_x64(x, row0, 0, tid, sbx[0]);  stage_w64(wfrag, 0, tid, sbw[0]);
        stage_x64(x, row0, 1, tid, sbx[1]);  stage_w64(wfrag, 1, tid, sbw[1]);

#define GSTEP(T, N)                                                          \
    {                                                                        \
        asm volatile("s_waitcnt vmcnt(" #N ")" ::: "memory");                \
        __builtin_amdgcn_s_barrier();                                        \
        compute64(sbx[(T) & 1], sbw[(T) & 1], lane, wid, acc);               \
        asm volatile("s_waitcnt lgkmcnt(0)" ::: "memory");                   \
        __builtin_amdgcn_s_barrier();                                        \
        if ((T) + 2 < NKT) {                                                 \
            stage_x64(x, row0, (T) + 2, tid, sbx[(T) & 1]);                  \
            stage_w64(wfrag, (T) + 2, tid, sbw[(T) & 1]);                    \
        }                                                                    \
    }
        GSTEP(0, 8)   GSTEP(1, 8)   GSTEP(2, 8)   GSTEP(3, 8)   GSTEP(4, 8)
        GSTEP(5, 8)   GSTEP(6, 8)   GSTEP(7, 8)   GSTEP(8, 8)   GSTEP(9, 8)
        GSTEP(10, 0)
#undef GSTEP

        f32x4* cur4 = (f32x4*)cur;
        size_t r4 = row0 + wid * 16 + ((lane >> 4) & 3) * 4;
#pragma unroll
        for (int n = 0; n < 4; ++n) {
            f32x4 q;
#pragma unroll
            for (int j = 0; j < 4; ++j) q[j] = acc[n][j] + bh4[n];
            cur4[(r4 >> 2) * 64 + n * 16 + (lane & 15)] = q;
        }
    }
}

// ---------------------------------------------------------------------------
// k2: LIF (round-8 structure, x REP_L repeats)
// ---------------------------------------------------------------------------
__global__ __launch_bounds__(64) void lif(const float* __restrict__ cur, ull* __restrict__ masks) {
    int b = blockIdx.x & 255;
    int c = blockIdx.x >> 8;
    int h = threadIdx.x;
    int t0 = c * TCL;
    int ts = (c == 0) ? 0 : (t0 - BIL);
    for (int rep = 0; rep < REP_L; ++rep) {
        const f32x4* p = (const f32x4*)cur + (((size_t)b * T_ + ts) >> 2) * 64 + h;
        float v = 0.0f;
        int ngb = (t0 - ts) >> 2;          // burn-in groups (0 or 10)
        for (int g = 0; g < ngb; ++g) {
            f32x4 q = p[g * 64];
#pragma unroll
            for (int j = 0; j < 4; ++j) {
                v = (v + q[j]) * 0.5f;
                v = (v >= 1.0f) ? 0.0f : v;
            }
        }
        p += (size_t)ngb * 64;
        ull* mp = masks + (size_t)b * T_ + t0;
#pragma unroll 2
        for (int g = 0; g < TCL / 4; ++g) {
            f32x4 q = p[g * 64];
#pragma unroll
            for (int j = 0; j < 4; ++j) {
                v = (v + q[j]) * 0.5f;
                bool s = (v >= 1.0f);
                ull m = __ballot(s);
                if (h == 0) mp[g * 4 + j] = m;
                v = s ? 0.0f : v;
            }
        }
    }
}

// ---------------------------------------------------------------------------
// k3: fused readout (round-8 structure; phases x REP_R, init once)
// ---------------------------------------------------------------------------
__global__ __launch_bounds__(512) void readout(const ull* __restrict__ masks,
                                               const float* __restrict__ Wr,
                                               const float* __restrict__ br,
                                               const float* __restrict__ tau,
                                               float* __restrict__ out) {
    __shared__ __align__(16) float wt[64][20];     // wt[h][o]
    __shared__ ull  smask[T_];
    __shared__ __align__(16) float E[NCH][20];
    __shared__ __align__(16) float Sv[NCH][20];
    __shared__ __align__(16) float pacc[NCH][20];
    __shared__ __align__(16) float sScale[20], sBase[20], sBeta[20];
    __shared__ float Pg[8][20], Sst[8][20], part[8][20];

    int tid = threadIdx.x;
    int b   = blockIdx.x;
    for (int i = tid; i < 1280; i += 512) wt[i & 63][i >> 6] = Wr[(size_t)(i >> 6) * 64 + (i & 63)];
    for (int i = tid; i < T_; i += 512) smask[i] = masks[(size_t)b * T_ + i];
    if (tid < 20) {
        float beta = 1.0f / (1.0f + __expf(-tau[tid]));
        sBeta[tid]  = beta;
        sScale[tid] = 1.0f - beta;
        sBase[tid]  = br[tid];
    }
    __syncthreads();

    for (int rep = 0; rep < REP_R; ++rep) {
        __syncthreads();

        // phase 1: scanE
        for (int it = tid; it < NCH * 5; it += 512) {
            int o4 = it % 5;
            int c  = it / 5;
            f32x4 beta4  = *(const f32x4*)&sBeta[o4 * 4];
            f32x4 scale4 = *(const f32x4*)&sScale[o4 * 4];
            f32x4 base4  = *(const f32x4*)&sBase[o4 * 4];
            f32x4 v = {0.f, 0.f, 0.f, 0.f};
            const ull* mp = smask + c * TCH;
#pragma unroll
            for (int j = 0; j < TCH; ++j) {
                ull m = mp[j];
                f32x4 a = {0.f, 0.f, 0.f, 0.f};
                while (m) {
                    int h = __builtin_ctzll(m);
                    m &= (m - 1);
                    a += *(const f32x4*)&wt[h][o4 * 4];
                }
                f32x4 q;
#pragma unroll
                for (int jj = 0; jj < 4; ++jj) q[jj] = scale4[jj] * (base4[jj] + a[jj]);
                v = beta4 * v + q;
            }
            *(f32x4*)&E[c][o4 * 4] = v;
        }
        __syncthreads();

        // phase 2a
        if (tid < 160) {
            int o = tid >> 3, g = tid & 7;
            float beta = sBeta[o];
            float b2 = beta * beta;
            float bp = b2 * b2 * beta;               // beta^5
            float P = 0.0f;
            for (int c = g * 25; c < g * 25 + 25; ++c) P = bp * P + E[c][o];
            Pg[g][o] = P;
        }
        __syncthreads();

        // phase 2b
        if (tid < 20) {
            int o = tid;
            float beta = sBeta[o];
            float b2 = beta * beta;
            float bp = b2 * b2 * beta;
            float bp25 = 1.0f;
#pragma unroll
            for (int i = 0; i < 25; ++i) bp25 *= bp;
            float s = 0.0f;
            for (int g = 0; g < 8; ++g) { Sst[g][o] = s; s = bp25 * s + Pg[g][o]; }
        }
        __syncthreads();

        // phase 2c
        if (tid < 160) {
            int o = tid >> 3, g = tid & 7;
            float beta = sBeta[o];
            float b2 = beta * beta;
            float bp = b2 * b2 * beta;
            float s = Sst[g][o];
            for (int c = g * 25; c < g * 25 + 25; ++c) { Sv[c][o] = s; s = bp * s + E[c][o]; }
        }
        __syncthreads();

        // phase 3: scanSoft
        if (tid < NCH) {
            int c = tid;
            float beta[20], v[20], acc[20];
#pragma unroll
            for (int o = 0; o < 20; ++o) {
                beta[o] = sBeta[o];
                v[o]   = Sv[c][o];
                acc[o] = 0.0f;
            }
            int t0 = c * TCH;
            const ull* mp = smask + t0;
#pragma unroll
            for (int j = 0; j < TCH; ++j) {
                int t = t0 + j;
                ull m = mp[j];
                f32x4 a[5];
#pragma unroll
                for (int i = 0; i < 5; ++i) a[i] = (f32x4){0.f, 0.f, 0.f, 0.f};
                while (m) {
                    int h = __builtin_ctzll(m);
                    m &= (m - 1);
                    const f32x4* w4 = (const f32x4*)&wt[h][0];
#pragma unroll
                    for (int i = 0; i < 5; ++i) a[i] += w4[i];
                }
#pragma unroll
                for (int o = 0; o < 20; ++o) {
                    float q = sScale[o] * (sBase[o] + a[o >> 2][o & 3]);
                    v[o] = beta[o] * v[o] + q;
                }
                if (t >= 11) {
                    float mx = v[0];
#pragma unroll
                    for (int o = 1; o < 20; ++o) mx = fmaxf(mx, v[o]);
                    float e[20], ssum = 0.0f;
#pragma unroll
                    for (int o = 0; o < 20; ++o) { e[o] = __expf(v[o] - mx); ssum += e[o]; }
                    float inv = 1.0f / ssum;
#pragma unroll
                    for (int o = 0; o < 20; ++o) acc[o] += e[o] * inv;
                }
            }
#pragma unroll
            for (int o = 0; o < 20; ++o) pacc[c][o] = acc[o];
        }
        __syncthreads();

        // phase 4: reduce
        if (tid < 160) {
            int o = tid >> 3, g = tid & 7;
            float s = 0.0f;
            for (int c = g * 25; c < g * 25 + 25; ++c) s += pacc[c][o];
            part[g][o] = s;
        }
        __syncthreads();
        if (tid < 20) {
            float s = 0.0f;
#pragma unroll
            for (int g = 0; g < 8; ++g) s += part[g][tid];
            out[(size_t)b * 20 + tid] = s;
        }
    }
}

// ---------------------------------------------------------------------------
extern "C" void kernel_launch(void* const* d_in, const int* in_sizes, int n_in,
                              void* d_out, int out_size, void* d_ws, size_t ws_size,
                              hipStream_t stream) {
    const float* x   = (const float*)d_in[0];
    const float* W_h = (const float*)d_in[1];
    const float* b_h = (const float*)d_in[2];
    const float* W_r = (const float*)d_in[3];
    const float* b_r = (const float*)d_in[4];
    const float* tau = (const float*)d_in[5];

    char* ws = (char*)d_ws;
    unsigned short* wfrag = (unsigned short*)(ws + OFF_WFRAG);
    float* cur  = (float*)(ws + OFF_CUR);
    ull*   msk  = (ull*)(ws + OFF_MASK);
    float* out  = (float*)d_out;

    wprep<<<22, 256, 0, stream>>>(W_h, wfrag);
    gemm_cur<<<4000, 256, 0, stream>>>(x, wfrag, b_h, cur);
    lif<<<NCL * 256, 64, 0, stream>>>(cur, msk);
    readout<<<256, 512, 0, stream>>>(msk, W_r, b_r, tau, out);
}

// Round 10
// 219.940 us; speedup vs baseline: 8.7824x; 8.7824x over previous
//
#include <hip/hip_runtime.h>

// ---------------------------------------------------------------------------
// VanillaSFNN fully fused: per-batch block does GEMM (MFMA, glds ring-2),
// exact sequential LIF from LDS currents, and the readout scan — one kernel.
//
//   k0 wprep : W_h f32 -> split bf16 hi/lo packed in MFMA fragment order (BK=64)
//   k1 fused : 256 blocks (1/batch) x 512 thr (8 waves, BM=128).
//              8 m-tiles x 11 k-steps; x+W staged via global_load_lds,
//              ring-2, counted vmcnt(6); after each m-tile: acc->LDS,
//              redundant-per-wave exact LIF -> masks in LDS; final phase:
//              readout scan (E/carry/scanSoft/reduce) from LDS masks.
// ---------------------------------------------------------------------------

typedef float  f32x4  __attribute__((ext_vector_type(4)));
typedef short  short8 __attribute__((ext_vector_type(8)));
typedef unsigned long long ull;

#define B_   256
#define T_   1000
#define K_   700
#define H_   64
#define O_   20
#define NKT  11          // k-tiles of BK=64 (704 padded)
#define NMT  8           // m-tiles of 128 rows (1024 padded)
#define NCH  200         // v_ro chunks
#define TCH  5           // chunk length

#define OFF_WFRAG  ((size_t)0)            // 11*16384 = 180,224 bytes

// ---------------------------------------------------------------------------
// k0: pack W_h into fragment-ordered split-bf16 (BK=64 tiles, zero-pad k>=700).
// Tile kt (16KB): hi 8KB then lo 8KB. Slot s=(nf*2+kf)*64+lane holds 8 bf16:
// h = nf*16+(lane&15), k = kt*64 + kf*32 + ((lane>>4)&3)*8 + j.
// ---------------------------------------------------------------------------
__global__ void wprep(const float* __restrict__ Wh, unsigned short* __restrict__ wfrag) {
    int e = blockIdx.x * 256 + threadIdx.x;          // 22*256 = 5632 exact
    int kt   = e >> 9;
    int rem  = e & 511;
    int nf   = rem >> 7;
    int kf   = (rem >> 6) & 1;
    int lane = rem & 63;
    int h     = nf * 16 + (lane & 15);
    int kbase = kt * 64 + kf * 32 + ((lane >> 4) & 3) * 8;
    int slot  = (nf * 2 + kf) * 64 + lane;
    unsigned short* dh = wfrag + (size_t)kt * 8192 + slot * 8;
    unsigned short* dl = dh + 4096;
#pragma unroll
    for (int j = 0; j < 8; ++j) {
        int k = kbase + j;
        float v = (k < K_) ? Wh[(size_t)h * K_ + k] : 0.0f;
        unsigned u  = __builtin_bit_cast(unsigned, v);
        float    fh = __builtin_bit_cast(float, u & 0xffff0000u);
        float    r  = v - fh;
        dh[j] = (unsigned short)(u >> 16);
        dl[j] = (unsigned short)(__builtin_bit_cast(unsigned, r) >> 16);
    }
}

// ---------------------------------------------------------------------------
// fused kernel helpers
// ---------------------------------------------------------------------------
__device__ __forceinline__ void glds16(const void* src, void* lds) {
    __builtin_amdgcn_global_load_lds(
        (const __attribute__((address_space(1))) void*)src,
        (__attribute__((address_space(3))) void*)lds, 16, 0, 0);
}

__device__ __forceinline__ void splitpair(f32x4 p0, f32x4 p1, short8& hi, short8& lo) {
#pragma unroll
    for (int j = 0; j < 4; ++j) {
        {
            unsigned u  = __builtin_bit_cast(unsigned, p0[j]);
            float    fh = __builtin_bit_cast(float, u & 0xffff0000u);
            float    r  = p0[j] - fh;
            hi[j] = (short)(u >> 16);
            lo[j] = (short)(__builtin_bit_cast(unsigned, r) >> 16);
        }
        {
            unsigned u  = __builtin_bit_cast(unsigned, p1[j]);
            float    fh = __builtin_bit_cast(float, u & 0xffff0000u);
            float    r  = p1[j] - fh;
            hi[j + 4] = (short)(u >> 16);
            lo[j + 4] = (short)(__builtin_bit_cast(unsigned, r) >> 16);
        }
    }
}

// stage x-tile (mt,kt): 128 rows x 64 k = 32KB = 2048 chunks; per-thread 4 glds.
// Two k-half subtiles [128 rows][128B]; phys chunk (r,pc) holds logical
// pc ^ (r&7) -> source pre-swizzled. Rows >= 1000 clamp to row 0 (LIF skips).
__device__ __forceinline__ void stage_x(const float* __restrict__ x, size_t brow0,
                                        int mt, int kt, int tid, float* sbuf) {
#pragma unroll
    for (int j = 0; j < 4; ++j) {
        int id = j * 512 + tid;                  // 0..2047
        int s2 = id >> 10;                       // k-half
        int r  = (id >> 3) & 127;                // row in tile
        int pc = id & 7;
        int c  = pc ^ (r & 7);                   // logical chunk
        int trow = mt * 128 + r;
        if (trow >= T_) trow = 0;                // pad rows: garbage, LIF skips
        int kbyte = kt * 256 + s2 * 128 + (c << 4);
        if (kbyte + 16 > K_ * 4) kbyte = 0;      // tail: value * W_pad(0) = 0
        const char* src = (const char*)(x + (brow0 + trow) * (size_t)K_) + kbyte;
        float* dst = sbuf + (size_t)(id & ~63) * 4;   // wave-uniform base + lane*16B
        glds16(src, dst);
    }
}

// stage W-tile kt: 16KB = 1024 chunks linear; per-thread 2 glds.
__device__ __forceinline__ void stage_w(const unsigned short* __restrict__ wfrag,
                                        int kt, int tid, unsigned short* sbuf) {
#pragma unroll
    for (int j = 0; j < 2; ++j) {
        int id = j * 512 + tid;                  // 0..1023
        const unsigned short* src = wfrag + (size_t)kt * 8192 + id * 8;
        unsigned short* dst = sbuf + (size_t)(id & ~63) * 8;
        glds16(src, dst);
    }
}

__device__ __forceinline__ void compute128(const float* sbx_, const unsigned short* sbw_,
                                           int lane, int wid, f32x4 (&acc)[4]) {
    const char*   xb = (const char*)sbx_;
    const short8* wb = (const short8*)sbw_;      // hi chunks 0..511, lo 512..1023
    int rloc = wid * 16 + (lane & 15);           // 0..127
    int g2   = ((lane >> 4) & 3) * 2;
#pragma unroll
    for (int kf = 0; kf < 2; ++kf) {
        const char* base = xb + kf * 16384 + rloc * 128;
        int c0 = g2 ^ (rloc & 7);
        int c1 = (g2 + 1) ^ (rloc & 7);
        f32x4 p0 = *(const f32x4*)(base + c0 * 16);
        f32x4 p1 = *(const f32x4*)(base + c1 * 16);
        short8 ah, al;
        splitpair(p0, p1, ah, al);
#pragma unroll
        for (int n = 0; n < 4; ++n) {
            short8 bhf = wb[(n * 2 + kf) * 64 + lane];
            short8 blf = wb[(n * 2 + kf) * 64 + lane + 512];
            acc[n] = __builtin_amdgcn_mfma_f32_16x16x32_bf16(ah, bhf, acc[n], 0, 0, 0);
            acc[n] = __builtin_amdgcn_mfma_f32_16x16x32_bf16(al, bhf, acc[n], 0, 0, 0);
            acc[n] = __builtin_amdgcn_mfma_f32_16x16x32_bf16(ah, blf, acc[n], 0, 0, 0);
        }
    }
}

// ---------------------------------------------------------------------------
// k1: fused GEMM + LIF + readout. One block per batch.
// LDS: pool 96KB (GEMM: x-ring 64K + W-ring 32K | readout: wt/E/Sv/pacc/...),
//      curT 32KB, smaskL 8KB  -> ~139KB, 1 block/CU.
// ---------------------------------------------------------------------------
__global__ __launch_bounds__(512, 2) void fused(const float* __restrict__ x,
                                                const unsigned short* __restrict__ wfrag,
                                                const float* __restrict__ b_h,
                                                const float* __restrict__ Wr,
                                                const float* __restrict__ br,
                                                const float* __restrict__ tau,
                                                float* __restrict__ out) {
    __shared__ __align__(16) char  pool[98304];
    __shared__ __align__(16) float curT[128 * 64];   // 32KB currents tile
    __shared__ ull smaskL[T_];                       // 8KB spike masks

    int tid  = threadIdx.x;
    int lane = tid & 63;
    int wid  = tid >> 6;             // 0..7
    int b    = blockIdx.x;
    size_t brow0 = (size_t)b * T_;

    float*          sbx0 = (float*)pool;
    float*          sbx1 = (float*)(pool + 32768);
    unsigned short* sbw0 = (unsigned short*)(pool + 65536);
    unsigned short* sbw1 = (unsigned short*)(pool + 81920);

    float bh4[4];
#pragma unroll
    for (int n = 0; n < 4; ++n) bh4[n] = b_h[n * 16 + (lane & 15)];

    f32x4 acc[4];
#pragma unroll
    for (int n = 0; n < 4; ++n) acc[n] = (f32x4){0.f, 0.f, 0.f, 0.f};
    float v = 0.0f;                  // LIF membrane, lane = neuron h

    // prologue: stage (0,0) and (0,1) -> 12 glds/thread outstanding
    stage_x(x, brow0, 0, 0, tid, sbx0);  stage_w(wfrag, 0, tid, sbw0);
    stage_x(x, brow0, 0, 1, tid, sbx1);  stage_w(wfrag, 1, tid, sbw1);

    int p = 0;
    for (int mt = 0; mt < NMT; ++mt) {
#pragma unroll
        for (int kt = 0; kt <= 10; ++kt) {
            float*          xb = p ? sbx1 : sbx0;
            unsigned short* wb = p ? sbw1 : sbw0;
            if (kt == 10 && mt == NMT - 1) {
                asm volatile("s_waitcnt vmcnt(0)" ::: "memory");
            } else {
                asm volatile("s_waitcnt vmcnt(6)" ::: "memory");
            }
            __builtin_amdgcn_s_barrier();
            compute128(xb, wb, lane, wid, acc);
            if (kt == 10) {
                // currents tile -> LDS (t-local = wid*16 + (lane>>4)*4 + j)
#pragma unroll
                for (int n = 0; n < 4; ++n) {
#pragma unroll
                    for (int j = 0; j < 4; ++j) {
                        int tloc = wid * 16 + ((lane >> 4) & 3) * 4 + j;
                        curT[tloc * 64 + n * 16 + (lane & 15)] = acc[n][j] + bh4[n];
                    }
                    acc[n] = (f32x4){0.f, 0.f, 0.f, 0.f};
                }
            }
            asm volatile("s_waitcnt lgkmcnt(0)" ::: "memory");
            __builtin_amdgcn_s_barrier();
            // stage step s+2
            int smt = mt, skt = kt + 2;
            if (skt >= NKT) { smt += 1; skt -= NKT; }
            if (smt < NMT) {
                stage_x(x, brow0, smt, skt, tid, xb);
                stage_w(wfrag, skt, tid, wb);
            }
            p ^= 1;
            if (kt == 10) {
                // exact sequential LIF over this tile (redundant in all waves)
                int tcnt = T_ - mt * 128; if (tcnt > 128) tcnt = 128;
                for (int j = 0; j < tcnt; ++j) {
                    float c = curT[j * 64 + lane];
                    v = (v + c) * 0.5f;
                    bool sp = (v >= 1.0f);
                    ull m = __ballot(sp);
                    if (wid == (j >> 4) && lane == 0) smaskL[mt * 128 + j] = m;
                    v = sp ? 0.0f : v;
                }
            }
        }
    }
    __syncthreads();   // smaskL visible; pool free for readout

    // ---------------- readout phase (from LDS masks) ----------------
    float* wt     = (float*)pool;                       //  5120 B: wt[h][o]
    float (*E)[20]    = (float(*)[20])(pool + 5120);    // 16000
    float (*Sv)[20]   = (float(*)[20])(pool + 21120);   // 16000
    float (*pacc)[20] = (float(*)[20])(pool + 37120);   // 16000
    float* sScale = (float*)(pool + 53120);
    float* sBase  = (float*)(pool + 53216);
    float* sBeta  = (float*)(pool + 53312);
    float (*Pg)[20]   = (float(*)[20])(pool + 53408);
    float (*Sst)[20]  = (float(*)[20])(pool + 54048);
    float (*part)[20] = (float(*)[20])(pool + 54688);

    for (int i = tid; i < 1280; i += 512) wt[(i & 63) * 20 + (i >> 6)] = Wr[(size_t)(i >> 6) * 64 + (i & 63)];
    if (tid < 20) {
        float beta = 1.0f / (1.0f + __expf(-tau[tid]));
        sBeta[tid]  = beta;
        sScale[tid] = 1.0f - beta;
        sBase[tid]  = br[tid];
    }
    __syncthreads();

    // phase 1: scanE — items (c, o4), NCH*5 = 1000
    for (int it = tid; it < NCH * 5; it += 512) {
        int o4 = it % 5;
        int c  = it / 5;
        f32x4 beta4  = *(const f32x4*)&sBeta[o4 * 4];
        f32x4 scale4 = *(const f32x4*)&sScale[o4 * 4];
        f32x4 base4  = *(const f32x4*)&sBase[o4 * 4];
        f32x4 vv = {0.f, 0.f, 0.f, 0.f};
        const ull* mp = smaskL + c * TCH;
#pragma unroll
        for (int j = 0; j < TCH; ++j) {
            ull m = mp[j];
            f32x4 a = {0.f, 0.f, 0.f, 0.f};
            while (m) {
                int h = __builtin_ctzll(m);
                m &= (m - 1);
                a += *(const f32x4*)&wt[h * 20 + o4 * 4];
            }
            f32x4 q;
#pragma unroll
            for (int jj = 0; jj < 4; ++jj) q[jj] = scale4[jj] * (base4[jj] + a[jj]);
            vv = beta4 * vv + q;
        }
        *(f32x4*)&E[c][o4 * 4] = vv;
    }
    __syncthreads();

    // phase 2a: per-(o, g) partial combine over 25 chunks
    if (tid < 160) {
        int o = tid >> 3, g = tid & 7;
        float beta = sBeta[o];
        float b2 = beta * beta;
        float bp = b2 * b2 * beta;               // beta^5
        float P = 0.0f;
        for (int c = g * 25; c < g * 25 + 25; ++c) P = bp * P + E[c][o];
        Pg[g][o] = P;
    }
    __syncthreads();

    // phase 2b: serial combine of 8 groups per o
    if (tid < 20) {
        int o = tid;
        float beta = sBeta[o];
        float b2 = beta * beta;
        float bp = b2 * b2 * beta;
        float bp25 = 1.0f;
#pragma unroll
        for (int i = 0; i < 25; ++i) bp25 *= bp;
        float s = 0.0f;
        for (int g = 0; g < 8; ++g) { Sst[g][o] = s; s = bp25 * s + Pg[g][o]; }
    }
    __syncthreads();

    // phase 2c: re-scan groups to per-chunk starts Sv
    if (tid < 160) {
        int o = tid >> 3, g = tid & 7;
        float beta = sBeta[o];
        float b2 = beta * beta;
        float bp = b2 * b2 * beta;
        float s = Sst[g][o];
        for (int c = g * 25; c < g * 25 + 25; ++c) { Sv[c][o] = s; s = bp * s + E[c][o]; }
    }
    __syncthreads();

    // phase 3: scanSoft — thread c < NCH
    if (tid < NCH) {
        int c = tid;
        float beta[20], vv[20], ac[20];
#pragma unroll
        for (int o = 0; o < 20; ++o) {
            beta[o] = sBeta[o];
            vv[o]  = Sv[c][o];
            ac[o]  = 0.0f;
        }
        int t0 = c * TCH;
        const ull* mp = smaskL + t0;
#pragma unroll
        for (int j = 0; j < TCH; ++j) {
            int t = t0 + j;
            ull m = mp[j];
            f32x4 a[5];
#pragma unroll
            for (int i = 0; i < 5; ++i) a[i] = (f32x4){0.f, 0.f, 0.f, 0.f};
            while (m) {
                int h = __builtin_ctzll(m);
                m &= (m - 1);
                const f32x4* w4 = (const f32x4*)&wt[h * 20];
#pragma unroll
                for (int i = 0; i < 5; ++i) a[i] += w4[i];
            }
#pragma unroll
            for (int o = 0; o < 20; ++o) {
                float q = sScale[o] * (sBase[o] + a[o >> 2][o & 3]);
                vv[o] = beta[o] * vv[o] + q;
            }
            if (t >= 11) {
                float mx = vv[0];
#pragma unroll
                for (int o = 1; o < 20; ++o) mx = fmaxf(mx, vv[o]);
                float e[20], ssum = 0.0f;
#pragma unroll
                for (int o = 0; o < 20; ++o) { e[o] = __expf(vv[o] - mx); ssum += e[o]; }
                float inv = 1.0f / ssum;
#pragma unroll
                for (int o = 0; o < 20; ++o) ac[o] += e[o] * inv;
            }
        }
#pragma unroll
        for (int o = 0; o < 20; ++o) pacc[c][o] = ac[o];
    }
    __syncthreads();

    // phase 4: reduce
    if (tid < 160) {
        int o = tid >> 3, g = tid & 7;
        float s = 0.0f;
        for (int c = g * 25; c < g * 25 + 25; ++c) s += pacc[c][o];
        part[g][o] = s;
    }
    __syncthreads();
    if (tid < 20) {
        float s = 0.0f;
#pragma unroll
        for (int g = 0; g < 8; ++g) s += part[g][tid];
        out[(size_t)b * 20 + tid] = s;
    }
}

// ---------------------------------------------------------------------------
extern "C" void kernel_launch(void* const* d_in, const int* in_sizes, int n_in,
                              void* d_out, int out_size, void* d_ws, size_t ws_size,
                              hipStream_t stream) {
    const float* x   = (const float*)d_in[0];
    const float* W_h = (const float*)d_in[1];
    const float* b_h = (const float*)d_in[2];
    const float* W_r = (const float*)d_in[3];
    const float* b_r = (const float*)d_in[4];
    const float* tau = (const float*)d_in[5];

    char* ws = (char*)d_ws;
    unsigned short* wfrag = (unsigned short*)(ws + OFF_WFRAG);
    float* out = (float*)d_out;

    wprep<<<22, 256, 0, stream>>>(W_h, wfrag);
    fused<<<B_, 512, 0, stream>>>(x, wfrag, b_h, W_r, b_r, tau, out);
}